// Round 20
// baseline (22.487 us; speedup 1.0000x reference)
//
#include <hip/hip_runtime.h>
#include <hip/hip_bf16.h>

// RDF with minimum-image PBC + Gaussian smearing, N=2048 atoms, 100 bins.
//
// Round-20: the ROOT CAUSE of every flaky failure (r14 0.25, r15 0.148,
// r18 0.545, r19 0.203) was the never-reset MODULO ticket: d_ws is
// poisoned to 0xAA, so the ticket starts at 170 (mod 256) and the
// "winner" (value===255 mod 256) is the 86th ARRIVER, not the last —
// it reads partials while ~170 blocks haven't published. r10-r13/r16
// passed on timing luck (in-flight publishes usually reach the IF before
// the winner's serialized readback gets to those rows).
// Fix: RESET the ticket each call with a 4-byte hipMemsetAsync node
// (graph-capture legal, validated r5-r7). Winner = stick==NBLOCKS-1 is
// then provably the LAST arriver. Handoff (each piece validated):
//  - publish: RETURNING atomicExch (r16): the sc0 returning form holds
//    vmcnt until the swap's old value returns from the coherence point
//    (IF), so after the vmcnt-draining __syncthreads ALL 100 swaps are
//    PERFORMED AT THE IF before thread 0's ticket RMW issues.
//  - ticket: flat relaxed fetch_add. The winner's RMW is 256th in the
//    ticket's coherence order; every prior RMW was real-time-after its
//    block's IF-performed swaps => all publishes precede the winner's
//    reads. One belt-and-braces ACQUIRE RMW by the winner.
//  - readback: SYSTEM-scope relaxed loads (bypass L1&L2, read at the
//    IF), coalesced, fixed-order reduce -> deterministic.
//
// Body (= r13/r16, invariant ~13us): 256 blocks x 1024 threads; block
// owns 8 rows of the cyclic upper-triangle enumeration (j=(i+1+t) mod N;
// one predicate dedups the d==N/2 diagonal; the x2 pair weight cancels
// in count normalization). i wave-uniform -> scalar i-loads; j-loads
// coalesced, L1-resident (xyz=24KB). ONE u32 LDS atomic per pair into a
// FINE distance histogram (17 sub-bins/bin, 4 private copies; integer
// counts -> exact, order-independent). Epilogue merges copies +
// convolves with a 103-tap Gaussian (stride 17 coprime with 32 banks ->
// conflict-free). Pairs with dist < 8 bin-units (~250 device-wide) take
// an exact f32 direct-smear path into bins 0..11 (tiny shell volumes
// amplify quantization error there).
// d_out = [count(100) | bins(101) | rdf(100)]. Graph = memset node (4B)
// + one kernel node.

#define N_ATOMS 2048
#define HALF    1024
#define NBINS   100
#define S_FINE  17          // fine sub-bins per coarse bin (coprime with 32)
#define FBINS   1744        // > 102.5 * 17 = 1742.5
#define NCOPY   4           // private fine-histogram copies
#define TAPS    103         // 2*3*17 + 1  (window +-3 bin widths)
#define NDIR    12          // exact direct-path coarse bins 0..11
#define TLOW    8.0f        // bin-units: below this, take the exact path
#define NBLOCKS 256
#define NTHREADS 1024
#define ROWS_PB 8           // N_ATOMS / NBLOCKS
#define PADB    112         // padded row stride for publish slots

__global__ __launch_bounds__(1024) void rdf_fused(
    const float* __restrict__ xyz,
    const float* __restrict__ cell,
    const float* __restrict__ offsets,
    const float* __restrict__ bins,
    float* __restrict__ out,
    float* __restrict__ partials,   // [NBLOCKS][PADB], exch-overwritten
    unsigned* __restrict__ ticket)  // RESET to 0 each call by memset node
{
    __shared__ unsigned fine[NCOPY][FBINS];  // private fine histograms (u32)
    __shared__ float wtab[TAPS];             // Gaussian taps
    __shared__ float conv[NBINS][8];         // conv partials / tail reduce
    __shared__ float cd[16];                 // exact direct-path coarse bins
    __shared__ float ssum[2];
    __shared__ unsigned stick;

    const int tid = threadIdx.x;
    const int bid = blockIdx.x;

    for (int a = tid; a < NCOPY * FBINS; a += NTHREADS)
        (&fine[0][0])[a] = 0u;
    if (tid < 16)   cd[tid] = 0.0f;
    if (tid < TAPS) {
        const float u = ((float)tid - 50.5f) * (1.0f / (float)S_FINE);
        wtab[tid] = __expf(-0.5f * u * u);
    }
    __syncthreads();

    const float cx = cell[0], cy = cell[1], cz = cell[2];
    const float hcx = 0.5f * cx, hcy = 0.5f * cy, hcz = 0.5f * cz;

    const float width = offsets[1] - offsets[0];   // 7.5/99
    const float invw  = 1.0f / width;
    // beyond 102.5 bin-units no bin k<=99 lies within the +-3w window
    const float cutd   = 102.5f * width;           // 7.765 < CUTOFF_B = 8.0
    const float cut2   = cutd * cutd;

    unsigned* const myfine = fine[tid >> 8];       // 4 waves per copy

    // ---- main loop: 8 rows per block, one 1024-wide j-sweep per row ----
    const int row0 = bid << 3;
    #pragma unroll
    for (int r = 0; r < ROWS_PB; ++r) {
        const int i = row0 + r;                    // wave-uniform
        const float xi = xyz[3 * i + 0];           // scalar loads
        const float yi = xyz[3 * i + 1];
        const float zi = xyz[3 * i + 2];
        if (tid == HALF - 1 && i >= HALF) continue; // dedup N/2 diagonal
        const int j = (i + 1 + tid) & (N_ATOMS - 1);

        float dx = xyz[3 * j + 0] - xi;            // coalesced, L1-resident
        float dy = xyz[3 * j + 1] - yi;
        float dz = xyz[3 * j + 2] - zi;
        // minimum-image wrap (matches reference shift semantics)
        dx += (dx >= hcx) ? -cx : ((dx < -hcx) ? cx : 0.0f);
        dy += (dy >= hcy) ? -cy : ((dy < -hcy) ? cy : 0.0f);
        dz += (dz >= hcz) ? -cz : ((dz < -hcz) ? cz : 0.0f);

        const float dsq = dx * dx + dy * dy + dz * dz;
        if (dsq < cut2 && dsq != 0.0f) {
            const float tu = sqrtf(dsq) * invw;    // dist in bin units
            if (tu >= TLOW) {
                // ONE native u32 LDS atomic/pair; lanes scatter over 1744
                atomicAdd(&myfine[(int)(tu * (float)S_FINE)], 1u);
            } else {
                // exact f32 path for low bins (~250 pairs device-wide)
                int khi = (int)tu + 4; if (khi > NDIR - 1) khi = NDIR - 1;
                for (int k = 0; k <= khi; ++k) {
                    const float e = tu - (float)k;
                    atomicAdd(&cd[k], __expf(-0.5f * e * e));
                }
            }
        }
    }

    __syncthreads();

    // merge the 4 copies into copy 0 (stride-1, conflict-free, int adds)
    for (int a = tid; a < FBINS; a += NTHREADS)
        fine[0][a] += fine[1][a] + fine[2][a] + fine[3][a];
    __syncthreads();

    // coarse[k] = sum_d wtab[d+51] * fine[17k+d]; stride-17 reads are
    // bank-conflict free (gcd(17,32)=1)
    if (tid < 400) {
        const int k = tid >> 2;
        const int c = tid & 3;
        const int m0 = c * 26;
        const int mcnt = (c == 3) ? 25 : 26;
        float s = 0.0f;
        for (int mm = 0; mm < mcnt; ++mm) {
            const int m = m0 + mm;
            const int f = S_FINE * k + m - 51;     // max 17*99+51 = 1734
            if (f >= 0) s += wtab[m] * (float)fine[0][f];  // exact: < 2^24
        }
        conv[k][c] = s;
    }
    __syncthreads();

    // ---- publish: RETURNING atomicExch into per-block-unique slots.
    // Returning (sc0) form completes vmcnt only when the old value comes
    // back from the IF -> after the barrier all swaps are PERFORMED there.
    if (tid < NBINS) {
        float raw = conv[tid][0] + conv[tid][1] + conv[tid][2] + conv[tid][3];
        if (tid < NDIR) raw += cd[tid];
        float old = atomicExch(&partials[bid * PADB + tid], raw);
        asm volatile("" :: "v"(old));   // keep return value live (sc0 form)
    }

    __syncthreads();
    if (tid == 0) {
        const unsigned so = __hip_atomic_fetch_add(
            ticket, 1u, __ATOMIC_RELAXED, __HIP_MEMORY_SCOPE_AGENT);
        unsigned last = (so == NBLOCKS - 1) ? 1u : 0u;  // TRUE last arriver
        if (last) {
            // belt-and-braces single acquire (cache invalidate)
            __hip_atomic_fetch_add(ticket, 0u,
                                   __ATOMIC_ACQUIRE, __HIP_MEMORY_SCOPE_AGENT);
        }
        stick = last;
    }
    __syncthreads();
    if (!stick) return;

    // ---- winner (provably last): SYSTEM-scope relaxed readback at the
    // IF. thread t: bin b=t&127, chunk c=t>>7; 32 blocks each, fixed order.
    {
        const int b = tid & 127;
        const int c = tid >> 7;
        if (b < NBINS) {
            float s = 0.0f;
            #pragma unroll 8
            for (int q = 0; q < NBLOCKS / 8; ++q) {
                const int blk = c * (NBLOCKS / 8) + q;
                s += __hip_atomic_load(&partials[blk * PADB + b],
                                       __ATOMIC_RELAXED,
                                       __HIP_MEMORY_SCOPE_SYSTEM);
            }
            conv[b][c] = s;
        }
    }
    __syncthreads();

    float raw = 0.0f;
    if (tid < NBINS) {
        #pragma unroll
        for (int c = 0; c < 8; ++c) raw += conv[tid][c];
    }
    if (tid < 128) {
        float v = raw;
        #pragma unroll
        for (int o = 32; o > 0; o >>= 1) v += __shfl_down(v, o);
        if ((tid & 63) == 0) ssum[tid >> 6] = v;
    }
    __syncthreads();
    const float S = ssum[0] + ssum[1];

    if (tid < NBINS) {
        const float cnt = raw / S;
        out[tid] = cnt;                                // count
        const float b0 = bins[tid], b1 = bins[tid + 1];
        const float R  = bins[NBINS];                  // R_END = 7.5
        // rdf = cnt / (vol_bin / V) = cnt * R^3 / (b1^3 - b0^3)  (4pi/3 cancels)
        out[201 + tid] = cnt * (R * R * R) / (b1 * b1 * b1 - b0 * b0 * b0);
    }
    if (tid < NBINS + 1) {
        out[100 + tid] = bins[tid];                    // bins passthrough
    }
}

extern "C" void kernel_launch(void* const* d_in, const int* in_sizes, int n_in,
                              void* d_out, int out_size, void* d_ws, size_t ws_size,
                              hipStream_t stream) {
    const float* xyz     = (const float*)d_in[0];
    const float* cell    = (const float*)d_in[1];
    const float* bins    = (const float*)d_in[2];
    const float* offsets = (const float*)d_in[3];
    float* out = (float*)d_out;

    float*    partials = (float*)d_ws;   // NBLOCKS*PADB floats, exch-overwritten
    unsigned* ticket   = (unsigned*)((char*)d_ws +
                                     (size_t)NBLOCKS * PADB * sizeof(float));

    // reset the ticket each call: winner is then provably the LAST arriver
    hipMemsetAsync(ticket, 0, sizeof(unsigned), stream);
    rdf_fused<<<NBLOCKS, NTHREADS, 0, stream>>>(xyz, cell, offsets, bins, out,
                                                partials, ticket);
}